// Round 7
// baseline (54.488 us; speedup 1.0000x reference)
//
#include <hip/hip_runtime.h>

// Deformable depthwise conv1d (fp32), MI355X.
// Round 7: explicit 3-phase software pipeline per iteration:
//   A(it): global windows -> packed conv -> clamp/cvt/fract (positions)
//   G(it): issue the 14 data-dependent ds_read2 gathers
//   C(it): blend + accumulate + store
// Steady-state body: A(it); LOADW(it+1); C(it-1); G(it)
// -> gather latency of G(it-1) hides under A(it)'s ~110 VALU ops.
// u[] double-buffered by compile-time (it&1); launch_bounds(256,4) lets
// VGPR grow (~100) instead of the compiler's 28-VGPR serialization.

constexpr int B_ = 8;
constexpr int C_ = 512;
constexpr int T_ = 4096;
constexpr int K_ = 7;
constexpr int T_OUT = T_ - K_ + 1;      // 4090
constexpr int BLOCK = 256;
constexpr int P_ = 16;                  // zero pad each side
constexpr int ROWP = P_ + T_ + P_;      // 4128 floats = 16.5 KB
constexpr int SPAN = 2 * BLOCK;         // 512 t per iter
constexpr int NIT = 8;

typedef float v2f __attribute__((ext_vector_type(2)));

__device__ __forceinline__ float fract_pos(float p) {
#if __has_builtin(__builtin_amdgcn_fractf)
    return __builtin_amdgcn_fractf(p);      // v_fract_f32 (p >= 0 here)
#else
    return p - floorf(p);
#endif
}

__device__ __forceinline__ float clamp01hi(float a, float hi) {
#if __has_builtin(__builtin_amdgcn_fmed3f)
    return __builtin_amdgcn_fmed3f(a, 0.0f, hi);   // v_med3_f32
#else
    return fminf(fmaxf(a, 0.0f), hi);
#endif
}

__global__ __launch_bounds__(BLOCK, 4)
void deform_dwconv1d_kernel(const float* __restrict__ x,
                            const float* __restrict__ weight,
                            const float* __restrict__ offset_w,
                            const float* __restrict__ offset_b,
                            float* __restrict__ out)
{
    __shared__ float rowp[ROWP];

    const int bc  = blockIdx.x;        // b*C + c
    const int c   = bc & (C_ - 1);
    const int tid = threadIdx.x;

    if (tid < P_) {
        rowp[tid] = 0.0f;
        rowp[P_ + T_ + tid] = 0.0f;
    }

    const float* xrow = x + (size_t)bc * T_;
    const float4* src = reinterpret_cast<const float4*>(xrow);
    float4* dst = reinterpret_cast<float4*>(rowp + P_);
    #pragma unroll
    for (int i = 0; i < T_ / 4 / BLOCK; ++i)
        dst[tid + i * BLOCK] = src[tid + i * BLOCK];

    float ow[K_ * K_];
    #pragma unroll
    for (int i = 0; i < K_ * K_; ++i) ow[i] = offset_w[c * K_ * K_ + i];
    float wgt[K_], obk[K_];
    #pragma unroll
    for (int k = 0; k < K_; ++k) {
        wgt[k] = weight[c * K_ + k];
        obk[k] = offset_b[c * K_ + k] + (float)k;
    }

    __syncthreads();

    float* orow = out + (size_t)bc * T_OUT;
    constexpr float HI = (float)(ROWP - 2);   // 4126: pad zeros beyond

    // ---- pipeline state (all indices compile-time after unroll) ----
    float wA[K_], wB[K_];                 // window buf (single)
    float uA[2][K_], uB[2][K_];           // fractions, dbuf by it&1
    int   idxA[K_], idxB[K_];             // gather element indices
    float g0A[K_], g1A[K_], g0B[K_], g1B[K_];

#define LOADW(IT) do {                                                        \
        const int tA_ = (IT) * SPAN + tid;                                    \
        const int tB_ = tA_ + BLOCK;                                          \
        const int tBw_ = ((IT) == NIT - 1) ? min(tB_, T_ - K_) : tB_;         \
        _Pragma("unroll")                                                     \
        for (int j = 0; j < K_; ++j) {                                        \
            wA[j] = xrow[tA_ + j];                                            \
            wB[j] = xrow[tBw_ + j];                                           \
        }                                                                     \
    } while (0)

#define PHASE_A(IT) do {                                                      \
        const int tA_ = (IT) * SPAN + tid;                                    \
        const v2f tf = {(float)(tA_ + P_), (float)(tA_ + BLOCK + P_)};        \
        _Pragma("unroll")                                                     \
        for (int k = 0; k < K_; ++k) {                                        \
            v2f o = tf + obk[k];                                              \
            _Pragma("unroll")                                                 \
            for (int j = 0; j < K_; ++j) {                                    \
                v2f w2 = {wA[j], wB[j]};                                      \
                v2f m2 = {ow[k * K_ + j], ow[k * K_ + j]};                    \
                o = __builtin_elementwise_fma(w2, m2, o);                     \
            }                                                                 \
            const float pA = clamp01hi(o.x, HI);                              \
            const float pB = clamp01hi(o.y, HI);                              \
            idxA[k] = (int)pA;                                                \
            idxB[k] = (int)pB;                                                \
            uA[(IT) & 1][k] = fract_pos(pA);                                  \
            uB[(IT) & 1][k] = fract_pos(pB);                                  \
        }                                                                     \
    } while (0)

#define PHASE_G(IT) do {                                                      \
        _Pragma("unroll")                                                     \
        for (int k = 0; k < K_; ++k) {                                        \
            g0A[k] = rowp[idxA[k]]; g1A[k] = rowp[idxA[k] + 1];               \
            g0B[k] = rowp[idxB[k]]; g1B[k] = rowp[idxB[k] + 1];               \
        }                                                                     \
    } while (0)

#define PHASE_C(IT) do {                                                      \
        const int tA_ = (IT) * SPAN + tid;                                    \
        const int tB_ = tA_ + BLOCK;                                          \
        float accA = 0.0f, accB = 0.0f;                                       \
        _Pragma("unroll")                                                     \
        for (int k = 0; k < K_; ++k) {                                        \
            const float sA = fmaf(uA[(IT) & 1][k], g1A[k] - g0A[k], g0A[k]);  \
            const float sB = fmaf(uB[(IT) & 1][k], g1B[k] - g0B[k], g0B[k]);  \
            accA = fmaf(sA, wgt[k], accA);                                    \
            accB = fmaf(sB, wgt[k], accB);                                    \
        }                                                                     \
        orow[tA_] = accA;                                                     \
        if ((IT) < NIT - 1 || tid < T_OUT - (NIT - 1) * SPAN - BLOCK)         \
            orow[tB_] = accB;                                                 \
    } while (0)

    // ---- prologue ----
    LOADW(0);
    PHASE_A(0);
    LOADW(1);
    PHASE_G(0);

    // ---- steady state ----
    #pragma unroll
    for (int it = 1; it < NIT; ++it) {
        PHASE_A(it);                 // covers G(it-1) gather latency
        if (it + 1 < NIT) LOADW(it + 1);
        PHASE_C(it - 1);             // consume gathers, free g regs
        PHASE_G(it);                 // issue next gathers
    }

    // ---- epilogue ----
    PHASE_C(NIT - 1);

#undef LOADW
#undef PHASE_A
#undef PHASE_G
#undef PHASE_C
}

extern "C" void kernel_launch(void* const* d_in, const int* in_sizes, int n_in,
                              void* d_out, int out_size, void* d_ws, size_t ws_size,
                              hipStream_t stream) {
    const float* x        = (const float*)d_in[0];
    const float* weight   = (const float*)d_in[1];
    const float* offset_w = (const float*)d_in[2];
    const float* offset_b = (const float*)d_in[3];
    float* out = (float*)d_out;

    deform_dwconv1d_kernel<<<B_ * C_, BLOCK, 0, stream>>>(
        x, weight, offset_w, offset_b, out);
}